// Round 12
// baseline (536.734 us; speedup 1.0000x reference)
//
#include <hip/hip_runtime.h>
#include <hip/hip_bf16.h>

#define N_NODES 50000
#define NREL 16
#define HID 64
#define NCLS 16
#define NTILES 3125            // N_NODES / 16
#define NBKT (N_NODES * NREL)  // 800000 buckets (dst*16 + rel)
#define SB 2048                // scan elems per block
#define NSB ((NBKT + SB - 1) / SB)  // 391
#define TBLK 196               // blocks per task-group (ceil(3125/16))
#define NGRP 6                 // task groups: 3+3+3+3+3+2

typedef __attribute__((ext_vector_type(8))) short bf16x8;
typedef __attribute__((ext_vector_type(4))) float f32x4;

static __device__ __forceinline__ unsigned short f2bf(float f) {
    __hip_bfloat16 h = __float2bfloat16(f);
    return *reinterpret_cast<unsigned short*>(&h);
}
static __device__ __forceinline__ float bf2f(unsigned short u) {
    __hip_bfloat16 h;
    *reinterpret_cast<unsigned short*>(&h) = u;
    return __bfloat162float(h);
}

// ---------------------------------------------------------------------------
// ws layout:
//   bcnt/rstart i32[800020] (zeroed; scan3 -> prefix IN PLACE)
//   | used u8[800000] (zeroed; key rel*50000+src, set by scat_k)
//   | rank i32[E] | bsum i32[512] | sedge int2[E] {src|(rel<<16), inv}
//   | WbT1 bf16[17*64*64] | WbT2 bf16[17*16*64]
//   | H1 bf16[16*50000*64]  SWIZZLED: row elem j holds col (j&3)*16+(j>>2)
//   | H2 bf16[16*50000*16] | X1m bf16[50000*64] (standard layout)
// ---------------------------------------------------------------------------

// K1: one atomic pass over buckets (dst*16+rel): count + per-edge rank
__global__ __launch_bounds__(256) void rank_k(const int* __restrict__ dstp,
                                              const int* __restrict__ et,
                                              int* __restrict__ bcnt,
                                              int* __restrict__ rank, int E) {
    int i = blockIdx.x * 256 + threadIdx.x;
    if (i < E) {
        int b = dstp[i] * NREL + et[i];
        rank[i] = atomicAdd(&bcnt[b], 1);
    }
}

// K2a: per-block sums of bcnt (2048 elems / block, 8 per thread)
__global__ __launch_bounds__(256) void scan1_k(const int* __restrict__ bcnt,
                                               int* __restrict__ bsum) {
    int b = blockIdx.x, t = threadIdx.x;
    int base = b * SB + t * 8;
    int s = 0;
#pragma unroll
    for (int j = 0; j < 8; ++j)
        if (base + j < NBKT) s += bcnt[base + j];
#pragma unroll
    for (int off = 1; off < 64; off <<= 1) s += __shfl_xor(s, off, 64);
    __shared__ int ws[4];
    if ((t & 63) == 0) ws[t >> 6] = s;
    __syncthreads();
    if (t == 0) bsum[b] = ws[0] + ws[1] + ws[2] + ws[3];
}

// K2b: exclusive scan of bsum[NSB] (one 512-thread block); rstart[NBKT] = E
__global__ __launch_bounds__(512) void scan2_k(int* __restrict__ bsum,
                                               int* __restrict__ rstart, int E) {
    __shared__ int ts[512];
    int t = threadIdx.x;
    int v = (t < NSB) ? bsum[t] : 0;
    ts[t] = v;
    __syncthreads();
    int acc = v;
    for (int off = 1; off < 512; off <<= 1) {
        int u = (t >= off) ? ts[t - off] : 0;
        __syncthreads();
        acc += u;
        ts[t] = acc;
        __syncthreads();
    }
    if (t < NSB) bsum[t] = acc - v;
    if (t == 0) rstart[NBKT] = E;
}

// K2c: per-block exclusive scan, IN PLACE (bcnt -> rstart)
__global__ __launch_bounds__(256) void scan3_k(int* __restrict__ bcnt,
                                               const int* __restrict__ bsum) {
    int b = blockIdx.x, t = threadIdx.x;
    int base = b * SB + t * 8;
    int a[8];
    int s = 0;
#pragma unroll
    for (int j = 0; j < 8; ++j) {
        a[j] = (base + j < NBKT) ? bcnt[base + j] : 0;
        s += a[j];
    }
    __shared__ int ts[256];
    ts[t] = s;
    __syncthreads();
    int acc = s;
    for (int off = 1; off < 256; off <<= 1) {
        int u = (t >= off) ? ts[t - off] : 0;
        __syncthreads();
        acc += u;
        ts[t] = acc;
        __syncthreads();
    }
    int run = bsum[b] + (acc - s);
#pragma unroll
    for (int j = 0; j < 8; ++j) {
        if (base + j < NBKT) bcnt[base + j] = run;
        run += a[j];
    }
}

// K3: atomic-free scatter + used-map
__global__ __launch_bounds__(256) void scat_k(const int* __restrict__ srcp,
                                              const int* __restrict__ dstp,
                                              const int* __restrict__ et,
                                              const int* __restrict__ rank,
                                              const int* __restrict__ rstart,
                                              int2* __restrict__ sedge,
                                              unsigned char* __restrict__ used,
                                              int E) {
    int i = blockIdx.x * 256 + threadIdx.x;
    if (i < E) {
        int r = et[i];
        int s = srcp[i];
        int b = dstp[i] * NREL + r;
        int lo = rstart[b], hi = rstart[b + 1];
        int p = lo + rank[i];
        float inv = 1.0f / (float)(hi - lo);
        sedge[p] = make_int2(s | (r << 16), __float_as_int(inv));
        used[r * N_NODES + s] = 1;
    }
}

// K4: build transposed bf16 weights only (task 16 = root)
__global__ __launch_bounds__(256) void cvtw_k(const float* __restrict__ W1,
                                              const float* __restrict__ root1,
                                              const float* __restrict__ W2,
                                              const float* __restrict__ root2,
                                              ushort* __restrict__ WbT1,
                                              ushort* __restrict__ WbT2) {
    int i = blockIdx.x * 256 + threadIdx.x;
    if (i < 17 * HID * HID) {
        int t = i >> 12;
        int rem = i & 4095;
        int n = rem >> 6, k = rem & 63;
        float v = (t < 16) ? W1[(size_t)t * HID * HID + k * HID + n]
                           : root1[k * HID + n];
        WbT1[i] = f2bf(v);
    } else {
        int j = i - 17 * HID * HID;
        if (j < 17 * NCLS * HID) {
            int t = j >> 10;
            int rem = j & 1023;
            int n = rem >> 6, k = rem & 63;
            float v = (t < 16) ? W2[(size_t)t * HID * NCLS + k * NCLS + n]
                               : root2[k * NCLS + n];
            WbT2[j] = f2bf(v);
        }
    }
}

// K5: MFMA transform 1 — 4 tiles (64 nodes) per wave, B-fragments loaded
// ONCE per task per wave (12x less weight L2 traffic). 6 task-groups for
// occupancy. H1 rows stored only if used (swizzled ushort4 packs).
__global__ __launch_bounds__(256) void trans1_k(const float* __restrict__ x,
                                                const ushort* __restrict__ WbT1,
                                                const float* __restrict__ b1,
                                                const unsigned char* __restrict__ used,
                                                ushort* __restrict__ H1,
                                                ushort* __restrict__ X1m) {
    int grp = blockIdx.x / TBLK;
    int blkin = blockIdx.x - grp * TBLK;
    int wave = threadIdx.x >> 6;
    int lane = threadIdx.x & 63;
    int mr = lane & 15;   // A row / D col
    int kq = lane >> 4;   // k-quad
    int tileBase = blkin * 16 + wave * 4;

    // A-fragments for up to 4 tiles (inline f32 -> bf16)
    bf16x8 a0[4], a1[4];
    int nvalid = 0;
#pragma unroll
    for (int q = 0; q < 4; ++q) {
        int tile = tileBase + q;
        if (tile < NTILES) {
            const float* xr = x + (size_t)(tile * 16 + mr) * HID + kq * 8;
            float4 f0 = *(const float4*)(xr);
            float4 f1 = *(const float4*)(xr + 4);
            float4 f2 = *(const float4*)(xr + 32);
            float4 f3 = *(const float4*)(xr + 36);
            bf16x8 t0v, t1v;
            t0v[0] = (short)f2bf(f0.x); t0v[1] = (short)f2bf(f0.y);
            t0v[2] = (short)f2bf(f0.z); t0v[3] = (short)f2bf(f0.w);
            t0v[4] = (short)f2bf(f1.x); t0v[5] = (short)f2bf(f1.y);
            t0v[6] = (short)f2bf(f1.z); t0v[7] = (short)f2bf(f1.w);
            t1v[0] = (short)f2bf(f2.x); t1v[1] = (short)f2bf(f2.y);
            t1v[2] = (short)f2bf(f2.z); t1v[3] = (short)f2bf(f2.w);
            t1v[4] = (short)f2bf(f3.x); t1v[5] = (short)f2bf(f3.y);
            t1v[6] = (short)f2bf(f3.z); t1v[7] = (short)f2bf(f3.w);
            a0[q] = t0v;
            a1[q] = t1v;
            nvalid = q + 1;
        }
    }

    int t0 = grp * 3;
    int t1 = (grp == NGRP - 1) ? 17 : (t0 + 3);

    for (int t = t0; t < t1; ++t) {
        const ushort* wt = WbT1 + (size_t)t * HID * HID + mr * HID + kq * 8;
        bf16x8 b0[4], bv[4];
#pragma unroll
        for (int nt = 0; nt < 4; ++nt) {
            b0[nt] = *(const bf16x8*)(wt + nt * 1024);
            bv[nt] = *(const bf16x8*)(wt + nt * 1024 + 32);
        }
        for (int q = 0; q < nvalid; ++q) {
            int n0 = (tileBase + q) * 16;
            f32x4 acc[4];
#pragma unroll
            for (int nt = 0; nt < 4; ++nt) {
                f32x4 c = {0.f, 0.f, 0.f, 0.f};
                c = __builtin_amdgcn_mfma_f32_16x16x32_bf16(a0[q], b0[nt], c, 0, 0, 0);
                c = __builtin_amdgcn_mfma_f32_16x16x32_bf16(a1[q], bv[nt], c, 0, 0, 0);
                acc[nt] = c;
            }
            if (t < 16) {
                uchar4 uf = *(const uchar4*)(used + (size_t)t * N_NODES + n0 + kq * 4);
                ushort* Ht = H1 + (size_t)t * N_NODES * HID;
#pragma unroll
                for (int r = 0; r < 4; ++r) {
                    unsigned char f = (r == 0) ? uf.x : (r == 1) ? uf.y
                                     : (r == 2) ? uf.z : uf.w;
                    if (f) {
                        int node = n0 + kq * 4 + r;  // D row = quad*4+reg
                        ushort4 o;
                        o.x = f2bf(acc[0][r]); o.y = f2bf(acc[1][r]);
                        o.z = f2bf(acc[2][r]); o.w = f2bf(acc[3][r]);
                        *(ushort4*)(Ht + (size_t)node * HID + mr * 4) = o;
                    }
                }
            } else {
#pragma unroll
                for (int nt = 0; nt < 4; ++nt) {
                    float bias = b1[nt * 16 + mr];
#pragma unroll
                    for (int r = 0; r < 4; ++r) {
                        int node = n0 + kq * 4 + r;
                        X1m[(size_t)node * HID + nt * 16 + mr] =
                            f2bf(acc[nt][r] + bias);
                    }
                }
            }
        }
    }
}

// K6: layer-1 gather. Wave owns dst node; lane j covers col (j&3)*16+(j>>2)
// (H1 swizzle). CSR bounds from rstart (dst*16 .. dst*16+16).
__global__ __launch_bounds__(256) void edge1_k(const int2* __restrict__ sedge,
                                               const int* __restrict__ rstart,
                                               const ushort* __restrict__ H1,
                                               ushort* __restrict__ X1m) {
    int wid = (blockIdx.x * 256 + threadIdx.x) >> 6;
    int lane = threadIdx.x & 63;
    if (wid >= N_NODES) return;
    int col = (lane & 3) * 16 + (lane >> 2);
    int lo = rstart[wid << 4], hi = rstart[(wid + 1) << 4];
    float acc = bf2f(X1m[(size_t)wid * HID + col]);
    int e = lo;
    for (; e + 4 <= hi; e += 4) {
        int2 m0 = sedge[e], m1 = sedge[e + 1], m2 = sedge[e + 2], m3 = sedge[e + 3];
        float v0 = bf2f(H1[((size_t)(m0.x >> 16) * N_NODES + (m0.x & 0xFFFF)) * HID + lane]);
        float v1 = bf2f(H1[((size_t)(m1.x >> 16) * N_NODES + (m1.x & 0xFFFF)) * HID + lane]);
        float v2 = bf2f(H1[((size_t)(m2.x >> 16) * N_NODES + (m2.x & 0xFFFF)) * HID + lane]);
        float v3 = bf2f(H1[((size_t)(m3.x >> 16) * N_NODES + (m3.x & 0xFFFF)) * HID + lane]);
        acc = fmaf(__int_as_float(m0.y), v0, acc);
        acc = fmaf(__int_as_float(m1.y), v1, acc);
        acc = fmaf(__int_as_float(m2.y), v2, acc);
        acc = fmaf(__int_as_float(m3.y), v3, acc);
    }
    for (; e < hi; ++e) {
        int2 m = sedge[e];
        float v = bf2f(H1[((size_t)(m.x >> 16) * N_NODES + (m.x & 0xFFFF)) * HID + lane]);
        acc = fmaf(__int_as_float(m.y), v, acc);
    }
    X1m[(size_t)wid * HID + col] = f2bf(fmaxf(acc, 0.f));  // relu folded
}

// K7: MFMA transform 2 — 4 tiles per wave, B-fragments once per task.
__global__ __launch_bounds__(256) void trans2_k(const ushort* __restrict__ X1m,
                                                const ushort* __restrict__ WbT2,
                                                const float* __restrict__ b2,
                                                const unsigned char* __restrict__ used,
                                                ushort* __restrict__ H2,
                                                float* __restrict__ out) {
    int grp = blockIdx.x / TBLK;
    int blkin = blockIdx.x - grp * TBLK;
    int wave = threadIdx.x >> 6;
    int lane = threadIdx.x & 63;
    int mr = lane & 15, kq = lane >> 4;
    int tileBase = blkin * 16 + wave * 4;

    bf16x8 a0[4], a1[4];
    int nvalid = 0;
#pragma unroll
    for (int q = 0; q < 4; ++q) {
        int tile = tileBase + q;
        if (tile < NTILES) {
            const bf16x8* arow =
                (const bf16x8*)(X1m + (size_t)(tile * 16 + mr) * HID + kq * 8);
            a0[q] = arow[0];
            a1[q] = arow[4];
            nvalid = q + 1;
        }
    }

    int t0 = grp * 3;
    int t1 = (grp == NGRP - 1) ? 17 : (t0 + 3);

    for (int t = t0; t < t1; ++t) {
        const ushort* wt = WbT2 + (size_t)t * NCLS * HID + mr * HID + kq * 8;
        bf16x8 b0 = *(const bf16x8*)(wt);
        bf16x8 bv = *(const bf16x8*)(wt + 32);
        for (int q = 0; q < nvalid; ++q) {
            int n0 = (tileBase + q) * 16;
            f32x4 c = {0.f, 0.f, 0.f, 0.f};
            c = __builtin_amdgcn_mfma_f32_16x16x32_bf16(a0[q], b0, c, 0, 0, 0);
            c = __builtin_amdgcn_mfma_f32_16x16x32_bf16(a1[q], bv, c, 0, 0, 0);
            if (t < 16) {
                uchar4 uf = *(const uchar4*)(used + (size_t)t * N_NODES + n0 + kq * 4);
                ushort* Ht = H2 + (size_t)t * N_NODES * NCLS;
#pragma unroll
                for (int r = 0; r < 4; ++r) {
                    unsigned char f = (r == 0) ? uf.x : (r == 1) ? uf.y
                                     : (r == 2) ? uf.z : uf.w;
                    if (f) {
                        int node = n0 + kq * 4 + r;
                        Ht[(size_t)node * NCLS + mr] = f2bf(c[r]);
                    }
                }
            } else {
                float bias = b2[mr];
#pragma unroll
                for (int r = 0; r < 4; ++r) {
                    int node = n0 + kq * 4 + r;
                    out[(size_t)node * NCLS + mr] = c[r] + bias;
                }
            }
        }
    }
}

// K8: layer-2 gather. 4 dst per wave (16-lane groups, lane = class).
__global__ __launch_bounds__(256) void edge2_k(const int2* __restrict__ sedge,
                                               const int* __restrict__ rstart,
                                               const ushort* __restrict__ H2,
                                               float* __restrict__ out) {
    int wid = (blockIdx.x * 256 + threadIdx.x) >> 6;
    int lane = threadIdx.x & 63;
    int g = lane >> 4, c = lane & 15;
    int d0 = wid * 4 + g;
    if (d0 < N_NODES) {
        int lo = rstart[d0 << 4], hi = rstart[(d0 + 1) << 4];
        float acc = out[(size_t)d0 * NCLS + c];
        int e = lo;
        for (; e + 2 <= hi; e += 2) {
            int2 m0 = sedge[e], m1 = sedge[e + 1];
            float v0 = bf2f(H2[((size_t)(m0.x >> 16) * N_NODES + (m0.x & 0xFFFF)) * NCLS + c]);
            float v1 = bf2f(H2[((size_t)(m1.x >> 16) * N_NODES + (m1.x & 0xFFFF)) * NCLS + c]);
            acc = fmaf(__int_as_float(m0.y), v0, acc);
            acc = fmaf(__int_as_float(m1.y), v1, acc);
        }
        if (e < hi) {
            int2 m = sedge[e];
            float v = bf2f(H2[((size_t)(m.x >> 16) * N_NODES + (m.x & 0xFFFF)) * NCLS + c]);
            acc = fmaf(__int_as_float(m.y), v, acc);
        }
        out[(size_t)d0 * NCLS + c] = acc;
    }
}

extern "C" void kernel_launch(void* const* d_in, const int* in_sizes, int n_in,
                              void* d_out, int out_size, void* d_ws, size_t ws_size,
                              hipStream_t stream) {
    const int* ei    = (const int*)d_in[0];
    const int* et    = (const int*)d_in[1];
    const float* x   = (const float*)d_in[2];
    const float* W1  = (const float*)d_in[3];
    const float* r1  = (const float*)d_in[4];
    const float* b1  = (const float*)d_in[5];
    const float* W2  = (const float*)d_in[6];
    const float* r2  = (const float*)d_in[7];
    const float* b2  = (const float*)d_in[8];
    float* out = (float*)d_out;

    int E = in_sizes[0] / 2;
    const int* srcp = ei;
    const int* dstp = ei + E;

    int*   bcnt   = (int*)d_ws;                 // doubles as rstart after scan3
    unsigned char* used = (unsigned char*)(bcnt + (NBKT + 20));  // 800000 B
    int*   rank   = (int*)(used + NBKT);
    int*   bsum   = rank + E;                   // 512 ints (NSB=391 used)
    int2*  sedge  = (int2*)(bsum + 512);
    ushort* WbT1  = (ushort*)(sedge + E);
    ushort* WbT2  = WbT1 + 17 * HID * HID;
    ushort* H1    = WbT2 + 17 * NCLS * HID;
    ushort* H2    = H1 + (size_t)NREL * N_NODES * HID;
    ushort* X1m   = H2 + (size_t)NREL * N_NODES * NCLS;
    int*   rstart = bcnt;                       // alias (in-place scan)

    hipMemsetAsync(bcnt, 0, (NBKT + 20) * sizeof(int) + NBKT, stream);

    int eb = (E + 255) / 256;
    int cvtThreads = 17 * HID * HID + 17 * NCLS * HID;

    cvtw_k<<<(cvtThreads + 255) / 256, 256, 0, stream>>>(W1, r1, W2, r2, WbT1, WbT2);
    rank_k<<<eb, 256, 0, stream>>>(dstp, et, bcnt, rank, E);
    scan1_k<<<NSB, 256, 0, stream>>>(bcnt, bsum);
    scan2_k<<<1, 512, 0, stream>>>(bsum, rstart, E);
    scan3_k<<<NSB, 256, 0, stream>>>(bcnt, bsum);
    scat_k<<<eb, 256, 0, stream>>>(srcp, dstp, et, rank, rstart, sedge, used, E);

    trans1_k<<<NGRP * TBLK, 256, 0, stream>>>(x, WbT1, b1, used, H1, X1m);
    edge1_k<<<(N_NODES + 3) / 4, 256, 0, stream>>>(sedge, rstart, H1, X1m);
    trans2_k<<<NGRP * TBLK, 256, 0, stream>>>(X1m, WbT2, b2, used, H2, out);
    edge2_k<<<(N_NODES / 4 + 3) / 4, 256, 0, stream>>>(sedge, rstart, H2, out);
}

// Round 13
// 284.874 us; speedup vs baseline: 1.8841x; 1.8841x over previous
//
#include <hip/hip_runtime.h>
#include <hip/hip_bf16.h>

#define N_NODES 50000
#define NREL 16
#define HID 64
#define NCLS 16
#define NTILES 3125            // N_NODES / 16
#define NBKT (N_NODES * NREL)  // 800000 buckets (dst*16 + rel)
#define SB 2048                // scan elems per block
#define NSB ((NBKT + SB - 1) / SB)  // 391
#define TBLK 196               // blocks per task-group (ceil(3125/16))
#define NGRP 6                 // task groups: 3+3+3+3+3+2

typedef __attribute__((ext_vector_type(8))) short bf16x8;
typedef __attribute__((ext_vector_type(4))) float f32x4;

static __device__ __forceinline__ unsigned short f2bf(float f) {
    __hip_bfloat16 h = __float2bfloat16(f);
    return *reinterpret_cast<unsigned short*>(&h);
}
static __device__ __forceinline__ float bf2f(unsigned short u) {
    __hip_bfloat16 h;
    *reinterpret_cast<unsigned short*>(&h) = u;
    return __bfloat162float(h);
}

// ---------------------------------------------------------------------------
// ws layout:
//   bcnt/rstart i32[800020] (zeroed; scan3 -> prefix IN PLACE)
//   | used u8[800000] (zeroed; key rel*50000+src, set by scat_k)
//   | rank i32[E] | bsum i32[512] | sedge int2[E] {src|(rel<<16), inv}
//   | WbT1 bf16[17*64*64] | WbT2 bf16[17*16*64]
//   | H1 bf16[16*50000*64]  SWIZZLED: row elem j holds col (j&3)*16+(j>>2)
//   | H2 bf16[16*50000*16] | X1m bf16[50000*64] (standard layout)
// ---------------------------------------------------------------------------

// K1: one atomic pass over buckets (dst*16+rel): count + per-edge rank
__global__ __launch_bounds__(256) void rank_k(const int* __restrict__ dstp,
                                              const int* __restrict__ et,
                                              int* __restrict__ bcnt,
                                              int* __restrict__ rank, int E) {
    int i = blockIdx.x * 256 + threadIdx.x;
    if (i < E) {
        int b = dstp[i] * NREL + et[i];
        rank[i] = atomicAdd(&bcnt[b], 1);
    }
}

// K2a: per-block sums of bcnt (2048 elems / block, 8 per thread)
__global__ __launch_bounds__(256) void scan1_k(const int* __restrict__ bcnt,
                                               int* __restrict__ bsum) {
    int b = blockIdx.x, t = threadIdx.x;
    int base = b * SB + t * 8;
    int s = 0;
#pragma unroll
    for (int j = 0; j < 8; ++j)
        if (base + j < NBKT) s += bcnt[base + j];
#pragma unroll
    for (int off = 1; off < 64; off <<= 1) s += __shfl_xor(s, off, 64);
    __shared__ int ws[4];
    if ((t & 63) == 0) ws[t >> 6] = s;
    __syncthreads();
    if (t == 0) bsum[b] = ws[0] + ws[1] + ws[2] + ws[3];
}

// K2b: exclusive scan of bsum[NSB] (one 512-thread block); rstart[NBKT] = E
__global__ __launch_bounds__(512) void scan2_k(int* __restrict__ bsum,
                                               int* __restrict__ rstart, int E) {
    __shared__ int ts[512];
    int t = threadIdx.x;
    int v = (t < NSB) ? bsum[t] : 0;
    ts[t] = v;
    __syncthreads();
    int acc = v;
    for (int off = 1; off < 512; off <<= 1) {
        int u = (t >= off) ? ts[t - off] : 0;
        __syncthreads();
        acc += u;
        ts[t] = acc;
        __syncthreads();
    }
    if (t < NSB) bsum[t] = acc - v;
    if (t == 0) rstart[NBKT] = E;
}

// K2c: per-block exclusive scan, IN PLACE (bcnt -> rstart)
__global__ __launch_bounds__(256) void scan3_k(int* __restrict__ bcnt,
                                               const int* __restrict__ bsum) {
    int b = blockIdx.x, t = threadIdx.x;
    int base = b * SB + t * 8;
    int a[8];
    int s = 0;
#pragma unroll
    for (int j = 0; j < 8; ++j) {
        a[j] = (base + j < NBKT) ? bcnt[base + j] : 0;
        s += a[j];
    }
    __shared__ int ts[256];
    ts[t] = s;
    __syncthreads();
    int acc = s;
    for (int off = 1; off < 256; off <<= 1) {
        int u = (t >= off) ? ts[t - off] : 0;
        __syncthreads();
        acc += u;
        ts[t] = acc;
        __syncthreads();
    }
    int run = bsum[b] + (acc - s);
#pragma unroll
    for (int j = 0; j < 8; ++j) {
        if (base + j < NBKT) bcnt[base + j] = run;
        run += a[j];
    }
}

// K3: atomic-free scatter + used-map
__global__ __launch_bounds__(256) void scat_k(const int* __restrict__ srcp,
                                              const int* __restrict__ dstp,
                                              const int* __restrict__ et,
                                              const int* __restrict__ rank,
                                              const int* __restrict__ rstart,
                                              int2* __restrict__ sedge,
                                              unsigned char* __restrict__ used,
                                              int E) {
    int i = blockIdx.x * 256 + threadIdx.x;
    if (i < E) {
        int r = et[i];
        int s = srcp[i];
        int b = dstp[i] * NREL + r;
        int lo = rstart[b], hi = rstart[b + 1];
        int p = lo + rank[i];
        float inv = 1.0f / (float)(hi - lo);
        sedge[p] = make_int2(s | (r << 16), __float_as_int(inv));
        used[r * N_NODES + s] = 1;
    }
}

// K4: build transposed bf16 weights only (task 16 = root)
__global__ __launch_bounds__(256) void cvtw_k(const float* __restrict__ W1,
                                              const float* __restrict__ root1,
                                              const float* __restrict__ W2,
                                              const float* __restrict__ root2,
                                              ushort* __restrict__ WbT1,
                                              ushort* __restrict__ WbT2) {
    int i = blockIdx.x * 256 + threadIdx.x;
    if (i < 17 * HID * HID) {
        int t = i >> 12;
        int rem = i & 4095;
        int n = rem >> 6, k = rem & 63;
        float v = (t < 16) ? W1[(size_t)t * HID * HID + k * HID + n]
                           : root1[k * HID + n];
        WbT1[i] = f2bf(v);
    } else {
        int j = i - 17 * HID * HID;
        if (j < 17 * NCLS * HID) {
            int t = j >> 10;
            int rem = j & 1023;
            int n = rem >> 6, k = rem & 63;
            float v = (t < 16) ? W2[(size_t)t * HID * NCLS + k * NCLS + n]
                               : root2[k * NCLS + n];
            WbT2[j] = f2bf(v);
        }
    }
}

// K5: MFMA transform 1 — 4 tiles (64 nodes) per wave, B-fragments loaded once
// per task per wave. Inner q-loop FULLY UNROLLED with compile-time indices
// (R11's runtime-bound loop caused dynamic reg-array indexing: 78% VALUBusy).
__global__ __launch_bounds__(256) void trans1_k(const float* __restrict__ x,
                                                const ushort* __restrict__ WbT1,
                                                const float* __restrict__ b1,
                                                const unsigned char* __restrict__ used,
                                                ushort* __restrict__ H1,
                                                ushort* __restrict__ X1m) {
    int grp = blockIdx.x / TBLK;
    int blkin = blockIdx.x - grp * TBLK;
    int wave = threadIdx.x >> 6;
    int lane = threadIdx.x & 63;
    int mr = lane & 15;   // A row / D col
    int kq = lane >> 4;   // k-quad
    int tileBase = blkin * 16 + wave * 4;

    bf16x8 a0[4] = {}, a1[4] = {};
#pragma unroll
    for (int q = 0; q < 4; ++q) {
        if (tileBase + q < NTILES) {
            const float* xr = x + (size_t)((tileBase + q) * 16 + mr) * HID + kq * 8;
            float4 f0 = *(const float4*)(xr);
            float4 f1 = *(const float4*)(xr + 4);
            float4 f2 = *(const float4*)(xr + 32);
            float4 f3 = *(const float4*)(xr + 36);
            bf16x8 t0v, t1v;
            t0v[0] = (short)f2bf(f0.x); t0v[1] = (short)f2bf(f0.y);
            t0v[2] = (short)f2bf(f0.z); t0v[3] = (short)f2bf(f0.w);
            t0v[4] = (short)f2bf(f1.x); t0v[5] = (short)f2bf(f1.y);
            t0v[6] = (short)f2bf(f1.z); t0v[7] = (short)f2bf(f1.w);
            t1v[0] = (short)f2bf(f2.x); t1v[1] = (short)f2bf(f2.y);
            t1v[2] = (short)f2bf(f2.z); t1v[3] = (short)f2bf(f2.w);
            t1v[4] = (short)f2bf(f3.x); t1v[5] = (short)f2bf(f3.y);
            t1v[6] = (short)f2bf(f3.z); t1v[7] = (short)f2bf(f3.w);
            a0[q] = t0v;
            a1[q] = t1v;
        }
    }

    int t0 = grp * 3;
    int t1 = (grp == NGRP - 1) ? 17 : (t0 + 3);

    for (int t = t0; t < t1; ++t) {
        const ushort* wt = WbT1 + (size_t)t * HID * HID + mr * HID + kq * 8;
        bf16x8 b0[4], bv[4];
#pragma unroll
        for (int nt = 0; nt < 4; ++nt) {
            b0[nt] = *(const bf16x8*)(wt + nt * 1024);
            bv[nt] = *(const bf16x8*)(wt + nt * 1024 + 32);
        }
#pragma unroll
        for (int q = 0; q < 4; ++q) {
            if (tileBase + q >= NTILES) continue;  // wave-uniform scalar branch
            int n0 = (tileBase + q) * 16;
            f32x4 acc[4];
#pragma unroll
            for (int nt = 0; nt < 4; ++nt) {
                f32x4 c = {0.f, 0.f, 0.f, 0.f};
                c = __builtin_amdgcn_mfma_f32_16x16x32_bf16(a0[q], b0[nt], c, 0, 0, 0);
                c = __builtin_amdgcn_mfma_f32_16x16x32_bf16(a1[q], bv[nt], c, 0, 0, 0);
                acc[nt] = c;
            }
            if (t < 16) {
                uchar4 uf = *(const uchar4*)(used + (size_t)t * N_NODES + n0 + kq * 4);
                ushort* Ht = H1 + (size_t)t * N_NODES * HID;
#pragma unroll
                for (int r = 0; r < 4; ++r) {
                    unsigned char f = (r == 0) ? uf.x : (r == 1) ? uf.y
                                     : (r == 2) ? uf.z : uf.w;
                    if (f) {
                        int node = n0 + kq * 4 + r;  // D row = quad*4+reg
                        ushort4 o;
                        o.x = f2bf(acc[0][r]); o.y = f2bf(acc[1][r]);
                        o.z = f2bf(acc[2][r]); o.w = f2bf(acc[3][r]);
                        *(ushort4*)(Ht + (size_t)node * HID + mr * 4) = o;
                    }
                }
            } else {
#pragma unroll
                for (int nt = 0; nt < 4; ++nt) {
                    float bias = b1[nt * 16 + mr];
#pragma unroll
                    for (int r = 0; r < 4; ++r) {
                        int node = n0 + kq * 4 + r;
                        X1m[(size_t)node * HID + nt * 16 + mr] =
                            f2bf(acc[nt][r] + bias);
                    }
                }
            }
        }
    }
}

// K6: layer-1 gather. Wave owns dst node; lane j covers col (j&3)*16+(j>>2)
// (H1 swizzle). CSR bounds from rstart (dst*16 .. dst*16+16).
__global__ __launch_bounds__(256) void edge1_k(const int2* __restrict__ sedge,
                                               const int* __restrict__ rstart,
                                               const ushort* __restrict__ H1,
                                               ushort* __restrict__ X1m) {
    int wid = (blockIdx.x * 256 + threadIdx.x) >> 6;
    int lane = threadIdx.x & 63;
    if (wid >= N_NODES) return;
    int col = (lane & 3) * 16 + (lane >> 2);
    int lo = rstart[wid << 4], hi = rstart[(wid + 1) << 4];
    float acc = bf2f(X1m[(size_t)wid * HID + col]);
    int e = lo;
    for (; e + 4 <= hi; e += 4) {
        int2 m0 = sedge[e], m1 = sedge[e + 1], m2 = sedge[e + 2], m3 = sedge[e + 3];
        float v0 = bf2f(H1[((size_t)(m0.x >> 16) * N_NODES + (m0.x & 0xFFFF)) * HID + lane]);
        float v1 = bf2f(H1[((size_t)(m1.x >> 16) * N_NODES + (m1.x & 0xFFFF)) * HID + lane]);
        float v2 = bf2f(H1[((size_t)(m2.x >> 16) * N_NODES + (m2.x & 0xFFFF)) * HID + lane]);
        float v3 = bf2f(H1[((size_t)(m3.x >> 16) * N_NODES + (m3.x & 0xFFFF)) * HID + lane]);
        acc = fmaf(__int_as_float(m0.y), v0, acc);
        acc = fmaf(__int_as_float(m1.y), v1, acc);
        acc = fmaf(__int_as_float(m2.y), v2, acc);
        acc = fmaf(__int_as_float(m3.y), v3, acc);
    }
    for (; e < hi; ++e) {
        int2 m = sedge[e];
        float v = bf2f(H1[((size_t)(m.x >> 16) * N_NODES + (m.x & 0xFFFF)) * HID + lane]);
        acc = fmaf(__int_as_float(m.y), v, acc);
    }
    X1m[(size_t)wid * HID + col] = f2bf(fmaxf(acc, 0.f));  // relu folded
}

// K7: MFMA transform 2 — 4 tiles per wave, B-fragments once per task.
// Same compile-time unroll fix.
__global__ __launch_bounds__(256) void trans2_k(const ushort* __restrict__ X1m,
                                                const ushort* __restrict__ WbT2,
                                                const float* __restrict__ b2,
                                                const unsigned char* __restrict__ used,
                                                ushort* __restrict__ H2,
                                                float* __restrict__ out) {
    int grp = blockIdx.x / TBLK;
    int blkin = blockIdx.x - grp * TBLK;
    int wave = threadIdx.x >> 6;
    int lane = threadIdx.x & 63;
    int mr = lane & 15, kq = lane >> 4;
    int tileBase = blkin * 16 + wave * 4;

    bf16x8 a0[4] = {}, a1[4] = {};
#pragma unroll
    for (int q = 0; q < 4; ++q) {
        if (tileBase + q < NTILES) {
            const bf16x8* arow =
                (const bf16x8*)(X1m + (size_t)((tileBase + q) * 16 + mr) * HID + kq * 8);
            a0[q] = arow[0];
            a1[q] = arow[4];
        }
    }

    int t0 = grp * 3;
    int t1 = (grp == NGRP - 1) ? 17 : (t0 + 3);

    for (int t = t0; t < t1; ++t) {
        const ushort* wt = WbT2 + (size_t)t * NCLS * HID + mr * HID + kq * 8;
        bf16x8 b0 = *(const bf16x8*)(wt);
        bf16x8 bv = *(const bf16x8*)(wt + 32);
#pragma unroll
        for (int q = 0; q < 4; ++q) {
            if (tileBase + q >= NTILES) continue;
            int n0 = (tileBase + q) * 16;
            f32x4 c = {0.f, 0.f, 0.f, 0.f};
            c = __builtin_amdgcn_mfma_f32_16x16x32_bf16(a0[q], b0, c, 0, 0, 0);
            c = __builtin_amdgcn_mfma_f32_16x16x32_bf16(a1[q], bv, c, 0, 0, 0);
            if (t < 16) {
                uchar4 uf = *(const uchar4*)(used + (size_t)t * N_NODES + n0 + kq * 4);
                ushort* Ht = H2 + (size_t)t * N_NODES * NCLS;
#pragma unroll
                for (int r = 0; r < 4; ++r) {
                    unsigned char f = (r == 0) ? uf.x : (r == 1) ? uf.y
                                     : (r == 2) ? uf.z : uf.w;
                    if (f) {
                        int node = n0 + kq * 4 + r;
                        Ht[(size_t)node * NCLS + mr] = f2bf(c[r]);
                    }
                }
            } else {
                float bias = b2[mr];
#pragma unroll
                for (int r = 0; r < 4; ++r) {
                    int node = n0 + kq * 4 + r;
                    out[(size_t)node * NCLS + mr] = c[r] + bias;
                }
            }
        }
    }
}

// K8: layer-2 gather. 4 dst per wave (16-lane groups, lane = class).
__global__ __launch_bounds__(256) void edge2_k(const int2* __restrict__ sedge,
                                               const int* __restrict__ rstart,
                                               const ushort* __restrict__ H2,
                                               float* __restrict__ out) {
    int wid = (blockIdx.x * 256 + threadIdx.x) >> 6;
    int lane = threadIdx.x & 63;
    int g = lane >> 4, c = lane & 15;
    int d0 = wid * 4 + g;
    if (d0 < N_NODES) {
        int lo = rstart[d0 << 4], hi = rstart[(d0 + 1) << 4];
        float acc = out[(size_t)d0 * NCLS + c];
        int e = lo;
        for (; e + 2 <= hi; e += 2) {
            int2 m0 = sedge[e], m1 = sedge[e + 1];
            float v0 = bf2f(H2[((size_t)(m0.x >> 16) * N_NODES + (m0.x & 0xFFFF)) * NCLS + c]);
            float v1 = bf2f(H2[((size_t)(m1.x >> 16) * N_NODES + (m1.x & 0xFFFF)) * NCLS + c]);
            acc = fmaf(__int_as_float(m0.y), v0, acc);
            acc = fmaf(__int_as_float(m1.y), v1, acc);
        }
        if (e < hi) {
            int2 m = sedge[e];
            float v = bf2f(H2[((size_t)(m.x >> 16) * N_NODES + (m.x & 0xFFFF)) * NCLS + c]);
            acc = fmaf(__int_as_float(m.y), v, acc);
        }
        out[(size_t)d0 * NCLS + c] = acc;
    }
}

extern "C" void kernel_launch(void* const* d_in, const int* in_sizes, int n_in,
                              void* d_out, int out_size, void* d_ws, size_t ws_size,
                              hipStream_t stream) {
    const int* ei    = (const int*)d_in[0];
    const int* et    = (const int*)d_in[1];
    const float* x   = (const float*)d_in[2];
    const float* W1  = (const float*)d_in[3];
    const float* r1  = (const float*)d_in[4];
    const float* b1  = (const float*)d_in[5];
    const float* W2  = (const float*)d_in[6];
    const float* r2  = (const float*)d_in[7];
    const float* b2  = (const float*)d_in[8];
    float* out = (float*)d_out;

    int E = in_sizes[0] / 2;
    const int* srcp = ei;
    const int* dstp = ei + E;

    int*   bcnt   = (int*)d_ws;                 // doubles as rstart after scan3
    unsigned char* used = (unsigned char*)(bcnt + (NBKT + 20));  // 800000 B
    int*   rank   = (int*)(used + NBKT);
    int*   bsum   = rank + E;                   // 512 ints (NSB=391 used)
    int2*  sedge  = (int2*)(bsum + 512);
    ushort* WbT1  = (ushort*)(sedge + E);
    ushort* WbT2  = WbT1 + 17 * HID * HID;
    ushort* H1    = WbT2 + 17 * NCLS * HID;
    ushort* H2    = H1 + (size_t)NREL * N_NODES * HID;
    ushort* X1m   = H2 + (size_t)NREL * N_NODES * NCLS;
    int*   rstart = bcnt;                       // alias (in-place scan)

    hipMemsetAsync(bcnt, 0, (NBKT + 20) * sizeof(int) + NBKT, stream);

    int eb = (E + 255) / 256;
    int cvtThreads = 17 * HID * HID + 17 * NCLS * HID;

    cvtw_k<<<(cvtThreads + 255) / 256, 256, 0, stream>>>(W1, r1, W2, r2, WbT1, WbT2);
    rank_k<<<eb, 256, 0, stream>>>(dstp, et, bcnt, rank, E);
    scan1_k<<<NSB, 256, 0, stream>>>(bcnt, bsum);
    scan2_k<<<1, 512, 0, stream>>>(bsum, rstart, E);
    scan3_k<<<NSB, 256, 0, stream>>>(bcnt, bsum);
    scat_k<<<eb, 256, 0, stream>>>(srcp, dstp, et, rank, rstart, sedge, used, E);

    trans1_k<<<NGRP * TBLK, 256, 0, stream>>>(x, WbT1, b1, used, H1, X1m);
    edge1_k<<<(N_NODES + 3) / 4, 256, 0, stream>>>(sedge, rstart, H1, X1m);
    trans2_k<<<NGRP * TBLK, 256, 0, stream>>>(X1m, WbT2, b2, used, H2, out);
    edge2_k<<<(N_NODES / 4 + 3) / 4, 256, 0, stream>>>(sedge, rstart, H2, out);
}

// Round 14
// 270.496 us; speedup vs baseline: 1.9843x; 1.0532x over previous
//
#include <hip/hip_runtime.h>
#include <hip/hip_bf16.h>

#define N_NODES 50000
#define NREL 16
#define HID 64
#define NCLS 16
#define NTILES 3125            // N_NODES / 16
#define NBKT (N_NODES * NREL)  // 800000 buckets (dst*16 + rel)
#define SB 2048                // scan elems per block
#define NSB ((NBKT + SB - 1) / SB)  // 391
#define TBLK 196               // blocks per task-group (ceil(3125/16))
#define NGRP 6                 // task groups: 3+3+3+3+3+2

typedef __attribute__((ext_vector_type(8))) short bf16x8;
typedef __attribute__((ext_vector_type(4))) float f32x4;

static __device__ __forceinline__ unsigned short f2bf(float f) {
    __hip_bfloat16 h = __float2bfloat16(f);
    return *reinterpret_cast<unsigned short*>(&h);
}
static __device__ __forceinline__ float bf2f(unsigned short u) {
    __hip_bfloat16 h;
    *reinterpret_cast<unsigned short*>(&h) = u;
    return __bfloat162float(h);
}

// ---------------------------------------------------------------------------
// ws layout:
//   bcnt/rstart i32[800020] (zeroed; scan3 -> prefix IN PLACE)
//   | used u8[800000] (zeroed; key rel*50000+src, set by scat_k)
//   | rank i32[E] | bsum i32[512] | sedge int2[E] {src|(rel<<16), inv}
//   | WbT1 bf16[17*64*64] | WbT2 bf16[17*16*64]
//   | H1 bf16[16*50000*64]  SWIZZLED: row elem j holds col (j&3)*16+(j>>2)
//   | H2 bf16[16*50000*16] | X1m bf16[50000*64] (standard layout)
// ---------------------------------------------------------------------------

// K1: one atomic pass over buckets (dst*16+rel): count + per-edge rank
__global__ __launch_bounds__(256) void rank_k(const int* __restrict__ dstp,
                                              const int* __restrict__ et,
                                              int* __restrict__ bcnt,
                                              int* __restrict__ rank, int E) {
    int i = blockIdx.x * 256 + threadIdx.x;
    if (i < E) {
        int b = dstp[i] * NREL + et[i];
        rank[i] = atomicAdd(&bcnt[b], 1);
    }
}

// K2a: per-block sums of bcnt (2048 elems / block, 8 per thread)
__global__ __launch_bounds__(256) void scan1_k(const int* __restrict__ bcnt,
                                               int* __restrict__ bsum) {
    int b = blockIdx.x, t = threadIdx.x;
    int base = b * SB + t * 8;
    int s = 0;
#pragma unroll
    for (int j = 0; j < 8; ++j)
        if (base + j < NBKT) s += bcnt[base + j];
#pragma unroll
    for (int off = 1; off < 64; off <<= 1) s += __shfl_xor(s, off, 64);
    __shared__ int ws[4];
    if ((t & 63) == 0) ws[t >> 6] = s;
    __syncthreads();
    if (t == 0) bsum[b] = ws[0] + ws[1] + ws[2] + ws[3];
}

// K2b: exclusive scan of bsum[NSB] (one 512-thread block); rstart[NBKT] = E
__global__ __launch_bounds__(512) void scan2_k(int* __restrict__ bsum,
                                               int* __restrict__ rstart, int E) {
    __shared__ int ts[512];
    int t = threadIdx.x;
    int v = (t < NSB) ? bsum[t] : 0;
    ts[t] = v;
    __syncthreads();
    int acc = v;
    for (int off = 1; off < 512; off <<= 1) {
        int u = (t >= off) ? ts[t - off] : 0;
        __syncthreads();
        acc += u;
        ts[t] = acc;
        __syncthreads();
    }
    if (t < NSB) bsum[t] = acc - v;
    if (t == 0) rstart[NBKT] = E;
}

// K2c: per-block exclusive scan, IN PLACE (bcnt -> rstart)
__global__ __launch_bounds__(256) void scan3_k(int* __restrict__ bcnt,
                                               const int* __restrict__ bsum) {
    int b = blockIdx.x, t = threadIdx.x;
    int base = b * SB + t * 8;
    int a[8];
    int s = 0;
#pragma unroll
    for (int j = 0; j < 8; ++j) {
        a[j] = (base + j < NBKT) ? bcnt[base + j] : 0;
        s += a[j];
    }
    __shared__ int ts[256];
    ts[t] = s;
    __syncthreads();
    int acc = s;
    for (int off = 1; off < 256; off <<= 1) {
        int u = (t >= off) ? ts[t - off] : 0;
        __syncthreads();
        acc += u;
        ts[t] = acc;
        __syncthreads();
    }
    int run = bsum[b] + (acc - s);
#pragma unroll
    for (int j = 0; j < 8; ++j) {
        if (base + j < NBKT) bcnt[base + j] = run;
        run += a[j];
    }
}

// K3: atomic-free scatter + used-map
__global__ __launch_bounds__(256) void scat_k(const int* __restrict__ srcp,
                                              const int* __restrict__ dstp,
                                              const int* __restrict__ et,
                                              const int* __restrict__ rank,
                                              const int* __restrict__ rstart,
                                              int2* __restrict__ sedge,
                                              unsigned char* __restrict__ used,
                                              int E) {
    int i = blockIdx.x * 256 + threadIdx.x;
    if (i < E) {
        int r = et[i];
        int s = srcp[i];
        int b = dstp[i] * NREL + r;
        int lo = rstart[b], hi = rstart[b + 1];
        int p = lo + rank[i];
        float inv = 1.0f / (float)(hi - lo);
        sedge[p] = make_int2(s | (r << 16), __float_as_int(inv));
        used[r * N_NODES + s] = 1;
    }
}

// K4: build transposed bf16 weights only (task 16 = root)
__global__ __launch_bounds__(256) void cvtw_k(const float* __restrict__ W1,
                                              const float* __restrict__ root1,
                                              const float* __restrict__ W2,
                                              const float* __restrict__ root2,
                                              ushort* __restrict__ WbT1,
                                              ushort* __restrict__ WbT2) {
    int i = blockIdx.x * 256 + threadIdx.x;
    if (i < 17 * HID * HID) {
        int t = i >> 12;
        int rem = i & 4095;
        int n = rem >> 6, k = rem & 63;
        float v = (t < 16) ? W1[(size_t)t * HID * HID + k * HID + n]
                           : root1[k * HID + n];
        WbT1[i] = f2bf(v);
    } else {
        int j = i - 17 * HID * HID;
        if (j < 17 * NCLS * HID) {
            int t = j >> 10;
            int rem = j & 1023;
            int n = rem >> 6, k = rem & 63;
            float v = (t < 16) ? W2[(size_t)t * HID * NCLS + k * NCLS + n]
                               : root2[k * NCLS + n];
            WbT2[j] = f2bf(v);
        }
    }
}

// K5: MFMA transform 1 — 4 tiles (64 nodes) per wave, B-fragments loaded once
// per task per wave, fully unrolled q-loop (compile-time reg indices).
__global__ __launch_bounds__(256) void trans1_k(const float* __restrict__ x,
                                                const ushort* __restrict__ WbT1,
                                                const float* __restrict__ b1,
                                                const unsigned char* __restrict__ used,
                                                ushort* __restrict__ H1,
                                                ushort* __restrict__ X1m) {
    int grp = blockIdx.x / TBLK;
    int blkin = blockIdx.x - grp * TBLK;
    int wave = threadIdx.x >> 6;
    int lane = threadIdx.x & 63;
    int mr = lane & 15;   // A row / D col
    int kq = lane >> 4;   // k-quad
    int tileBase = blkin * 16 + wave * 4;

    bf16x8 a0[4] = {}, a1[4] = {};
#pragma unroll
    for (int q = 0; q < 4; ++q) {
        if (tileBase + q < NTILES) {
            const float* xr = x + (size_t)((tileBase + q) * 16 + mr) * HID + kq * 8;
            float4 f0 = *(const float4*)(xr);
            float4 f1 = *(const float4*)(xr + 4);
            float4 f2 = *(const float4*)(xr + 32);
            float4 f3 = *(const float4*)(xr + 36);
            bf16x8 t0v, t1v;
            t0v[0] = (short)f2bf(f0.x); t0v[1] = (short)f2bf(f0.y);
            t0v[2] = (short)f2bf(f0.z); t0v[3] = (short)f2bf(f0.w);
            t0v[4] = (short)f2bf(f1.x); t0v[5] = (short)f2bf(f1.y);
            t0v[6] = (short)f2bf(f1.z); t0v[7] = (short)f2bf(f1.w);
            t1v[0] = (short)f2bf(f2.x); t1v[1] = (short)f2bf(f2.y);
            t1v[2] = (short)f2bf(f2.z); t1v[3] = (short)f2bf(f2.w);
            t1v[4] = (short)f2bf(f3.x); t1v[5] = (short)f2bf(f3.y);
            t1v[6] = (short)f2bf(f3.z); t1v[7] = (short)f2bf(f3.w);
            a0[q] = t0v;
            a1[q] = t1v;
        }
    }

    int t0 = grp * 3;
    int t1 = (grp == NGRP - 1) ? 17 : (t0 + 3);

    for (int t = t0; t < t1; ++t) {
        const ushort* wt = WbT1 + (size_t)t * HID * HID + mr * HID + kq * 8;
        bf16x8 b0[4], bv[4];
#pragma unroll
        for (int nt = 0; nt < 4; ++nt) {
            b0[nt] = *(const bf16x8*)(wt + nt * 1024);
            bv[nt] = *(const bf16x8*)(wt + nt * 1024 + 32);
        }
#pragma unroll
        for (int q = 0; q < 4; ++q) {
            if (tileBase + q >= NTILES) continue;  // wave-uniform scalar branch
            int n0 = (tileBase + q) * 16;
            f32x4 acc[4];
#pragma unroll
            for (int nt = 0; nt < 4; ++nt) {
                f32x4 c = {0.f, 0.f, 0.f, 0.f};
                c = __builtin_amdgcn_mfma_f32_16x16x32_bf16(a0[q], b0[nt], c, 0, 0, 0);
                c = __builtin_amdgcn_mfma_f32_16x16x32_bf16(a1[q], bv[nt], c, 0, 0, 0);
                acc[nt] = c;
            }
            if (t < 16) {
                uchar4 uf = *(const uchar4*)(used + (size_t)t * N_NODES + n0 + kq * 4);
                ushort* Ht = H1 + (size_t)t * N_NODES * HID;
#pragma unroll
                for (int r = 0; r < 4; ++r) {
                    unsigned char f = (r == 0) ? uf.x : (r == 1) ? uf.y
                                     : (r == 2) ? uf.z : uf.w;
                    if (f) {
                        int node = n0 + kq * 4 + r;  // D row = quad*4+reg
                        ushort4 o;
                        o.x = f2bf(acc[0][r]); o.y = f2bf(acc[1][r]);
                        o.z = f2bf(acc[2][r]); o.w = f2bf(acc[3][r]);
                        *(ushort4*)(Ht + (size_t)node * HID + mr * 4) = o;
                    }
                }
            } else {
#pragma unroll
                for (int nt = 0; nt < 4; ++nt) {
                    float bias = b1[nt * 16 + mr];
#pragma unroll
                    for (int r = 0; r < 4; ++r) {
                        int node = n0 + kq * 4 + r;
                        X1m[(size_t)node * HID + nt * 16 + mr] =
                            f2bf(acc[nt][r] + bias);
                    }
                }
            }
        }
    }
}

// K6: layer-1 gather. Wave owns dst node (scalarized wid); 8-deep unroll with
// dual accumulators for MLP; lane j covers col (j&3)*16+(j>>2) (H1 swizzle).
__global__ __launch_bounds__(256) void edge1_k(const int2* __restrict__ sedge,
                                               const int* __restrict__ rstart,
                                               const ushort* __restrict__ H1,
                                               ushort* __restrict__ X1m) {
    int wid = __builtin_amdgcn_readfirstlane((blockIdx.x * 256 + threadIdx.x) >> 6);
    int lane = threadIdx.x & 63;
    if (wid >= N_NODES) return;
    int col = (lane & 3) * 16 + (lane >> 2);
    int lo = rstart[wid << 4], hi = rstart[(wid + 1) << 4];
    float accA = bf2f(X1m[(size_t)wid * HID + col]);
    float accB = 0.0f;
    int e = lo;
    for (; e + 8 <= hi; e += 8) {
        int2 m0 = sedge[e],     m1 = sedge[e + 1], m2 = sedge[e + 2], m3 = sedge[e + 3];
        int2 m4 = sedge[e + 4], m5 = sedge[e + 5], m6 = sedge[e + 6], m7 = sedge[e + 7];
        float v0 = bf2f(H1[((size_t)(m0.x >> 16) * N_NODES + (m0.x & 0xFFFF)) * HID + lane]);
        float v1 = bf2f(H1[((size_t)(m1.x >> 16) * N_NODES + (m1.x & 0xFFFF)) * HID + lane]);
        float v2 = bf2f(H1[((size_t)(m2.x >> 16) * N_NODES + (m2.x & 0xFFFF)) * HID + lane]);
        float v3 = bf2f(H1[((size_t)(m3.x >> 16) * N_NODES + (m3.x & 0xFFFF)) * HID + lane]);
        float v4 = bf2f(H1[((size_t)(m4.x >> 16) * N_NODES + (m4.x & 0xFFFF)) * HID + lane]);
        float v5 = bf2f(H1[((size_t)(m5.x >> 16) * N_NODES + (m5.x & 0xFFFF)) * HID + lane]);
        float v6 = bf2f(H1[((size_t)(m6.x >> 16) * N_NODES + (m6.x & 0xFFFF)) * HID + lane]);
        float v7 = bf2f(H1[((size_t)(m7.x >> 16) * N_NODES + (m7.x & 0xFFFF)) * HID + lane]);
        accA = fmaf(__int_as_float(m0.y), v0, accA);
        accB = fmaf(__int_as_float(m1.y), v1, accB);
        accA = fmaf(__int_as_float(m2.y), v2, accA);
        accB = fmaf(__int_as_float(m3.y), v3, accB);
        accA = fmaf(__int_as_float(m4.y), v4, accA);
        accB = fmaf(__int_as_float(m5.y), v5, accB);
        accA = fmaf(__int_as_float(m6.y), v6, accA);
        accB = fmaf(__int_as_float(m7.y), v7, accB);
    }
    for (; e + 4 <= hi; e += 4) {
        int2 m0 = sedge[e], m1 = sedge[e + 1], m2 = sedge[e + 2], m3 = sedge[e + 3];
        float v0 = bf2f(H1[((size_t)(m0.x >> 16) * N_NODES + (m0.x & 0xFFFF)) * HID + lane]);
        float v1 = bf2f(H1[((size_t)(m1.x >> 16) * N_NODES + (m1.x & 0xFFFF)) * HID + lane]);
        float v2 = bf2f(H1[((size_t)(m2.x >> 16) * N_NODES + (m2.x & 0xFFFF)) * HID + lane]);
        float v3 = bf2f(H1[((size_t)(m3.x >> 16) * N_NODES + (m3.x & 0xFFFF)) * HID + lane]);
        accA = fmaf(__int_as_float(m0.y), v0, accA);
        accB = fmaf(__int_as_float(m1.y), v1, accB);
        accA = fmaf(__int_as_float(m2.y), v2, accA);
        accB = fmaf(__int_as_float(m3.y), v3, accB);
    }
    for (; e < hi; ++e) {
        int2 m = sedge[e];
        float v = bf2f(H1[((size_t)(m.x >> 16) * N_NODES + (m.x & 0xFFFF)) * HID + lane]);
        accA = fmaf(__int_as_float(m.y), v, accA);
    }
    float acc = accA + accB;
    X1m[(size_t)wid * HID + col] = f2bf(fmaxf(acc, 0.f));  // relu folded
}

// K7: MFMA transform 2 — 4 tiles per wave, B-fragments once per task.
__global__ __launch_bounds__(256) void trans2_k(const ushort* __restrict__ X1m,
                                                const ushort* __restrict__ WbT2,
                                                const float* __restrict__ b2,
                                                const unsigned char* __restrict__ used,
                                                ushort* __restrict__ H2,
                                                float* __restrict__ out) {
    int grp = blockIdx.x / TBLK;
    int blkin = blockIdx.x - grp * TBLK;
    int wave = threadIdx.x >> 6;
    int lane = threadIdx.x & 63;
    int mr = lane & 15, kq = lane >> 4;
    int tileBase = blkin * 16 + wave * 4;

    bf16x8 a0[4] = {}, a1[4] = {};
#pragma unroll
    for (int q = 0; q < 4; ++q) {
        if (tileBase + q < NTILES) {
            const bf16x8* arow =
                (const bf16x8*)(X1m + (size_t)((tileBase + q) * 16 + mr) * HID + kq * 8);
            a0[q] = arow[0];
            a1[q] = arow[4];
        }
    }

    int t0 = grp * 3;
    int t1 = (grp == NGRP - 1) ? 17 : (t0 + 3);

    for (int t = t0; t < t1; ++t) {
        const ushort* wt = WbT2 + (size_t)t * NCLS * HID + mr * HID + kq * 8;
        bf16x8 b0 = *(const bf16x8*)(wt);
        bf16x8 bv = *(const bf16x8*)(wt + 32);
#pragma unroll
        for (int q = 0; q < 4; ++q) {
            if (tileBase + q >= NTILES) continue;
            int n0 = (tileBase + q) * 16;
            f32x4 c = {0.f, 0.f, 0.f, 0.f};
            c = __builtin_amdgcn_mfma_f32_16x16x32_bf16(a0[q], b0, c, 0, 0, 0);
            c = __builtin_amdgcn_mfma_f32_16x16x32_bf16(a1[q], bv, c, 0, 0, 0);
            if (t < 16) {
                uchar4 uf = *(const uchar4*)(used + (size_t)t * N_NODES + n0 + kq * 4);
                ushort* Ht = H2 + (size_t)t * N_NODES * NCLS;
#pragma unroll
                for (int r = 0; r < 4; ++r) {
                    unsigned char f = (r == 0) ? uf.x : (r == 1) ? uf.y
                                     : (r == 2) ? uf.z : uf.w;
                    if (f) {
                        int node = n0 + kq * 4 + r;
                        Ht[(size_t)node * NCLS + mr] = f2bf(c[r]);
                    }
                }
            } else {
                float bias = b2[mr];
#pragma unroll
                for (int r = 0; r < 4; ++r) {
                    int node = n0 + kq * 4 + r;
                    out[(size_t)node * NCLS + mr] = c[r] + bias;
                }
            }
        }
    }
}

// K8: layer-2 gather. 4 dst per wave (16-lane groups, lane = class).
__global__ __launch_bounds__(256) void edge2_k(const int2* __restrict__ sedge,
                                               const int* __restrict__ rstart,
                                               const ushort* __restrict__ H2,
                                               float* __restrict__ out) {
    int wid = __builtin_amdgcn_readfirstlane((blockIdx.x * 256 + threadIdx.x) >> 6);
    int lane = threadIdx.x & 63;
    int g = lane >> 4, c = lane & 15;
    int d0 = wid * 4 + g;
    if (d0 < N_NODES) {
        int lo = rstart[d0 << 4], hi = rstart[(d0 + 1) << 4];
        float accA = out[(size_t)d0 * NCLS + c];
        float accB = 0.0f;
        int e = lo;
        for (; e + 4 <= hi; e += 4) {
            int2 m0 = sedge[e], m1 = sedge[e + 1], m2 = sedge[e + 2], m3 = sedge[e + 3];
            float v0 = bf2f(H2[((size_t)(m0.x >> 16) * N_NODES + (m0.x & 0xFFFF)) * NCLS + c]);
            float v1 = bf2f(H2[((size_t)(m1.x >> 16) * N_NODES + (m1.x & 0xFFFF)) * NCLS + c]);
            float v2 = bf2f(H2[((size_t)(m2.x >> 16) * N_NODES + (m2.x & 0xFFFF)) * NCLS + c]);
            float v3 = bf2f(H2[((size_t)(m3.x >> 16) * N_NODES + (m3.x & 0xFFFF)) * NCLS + c]);
            accA = fmaf(__int_as_float(m0.y), v0, accA);
            accB = fmaf(__int_as_float(m1.y), v1, accB);
            accA = fmaf(__int_as_float(m2.y), v2, accA);
            accB = fmaf(__int_as_float(m3.y), v3, accB);
        }
        for (; e < hi; ++e) {
            int2 m = sedge[e];
            float v = bf2f(H2[((size_t)(m.x >> 16) * N_NODES + (m.x & 0xFFFF)) * NCLS + c]);
            accA = fmaf(__int_as_float(m.y), v, accA);
        }
        out[(size_t)d0 * NCLS + c] = accA + accB;
    }
}

extern "C" void kernel_launch(void* const* d_in, const int* in_sizes, int n_in,
                              void* d_out, int out_size, void* d_ws, size_t ws_size,
                              hipStream_t stream) {
    const int* ei    = (const int*)d_in[0];
    const int* et    = (const int*)d_in[1];
    const float* x   = (const float*)d_in[2];
    const float* W1  = (const float*)d_in[3];
    const float* r1  = (const float*)d_in[4];
    const float* b1  = (const float*)d_in[5];
    const float* W2  = (const float*)d_in[6];
    const float* r2  = (const float*)d_in[7];
    const float* b2  = (const float*)d_in[8];
    float* out = (float*)d_out;

    int E = in_sizes[0] / 2;
    const int* srcp = ei;
    const int* dstp = ei + E;

    int*   bcnt   = (int*)d_ws;                 // doubles as rstart after scan3
    unsigned char* used = (unsigned char*)(bcnt + (NBKT + 20));  // 800000 B
    int*   rank   = (int*)(used + NBKT);
    int*   bsum   = rank + E;                   // 512 ints (NSB=391 used)
    int2*  sedge  = (int2*)(bsum + 512);
    ushort* WbT1  = (ushort*)(sedge + E);
    ushort* WbT2  = WbT1 + 17 * HID * HID;
    ushort* H1    = WbT2 + 17 * NCLS * HID;
    ushort* H2    = H1 + (size_t)NREL * N_NODES * HID;
    ushort* X1m   = H2 + (size_t)NREL * N_NODES * NCLS;
    int*   rstart = bcnt;                       // alias (in-place scan)

    hipMemsetAsync(bcnt, 0, (NBKT + 20) * sizeof(int) + NBKT, stream);

    int eb = (E + 255) / 256;
    int cvtThreads = 17 * HID * HID + 17 * NCLS * HID;

    cvtw_k<<<(cvtThreads + 255) / 256, 256, 0, stream>>>(W1, r1, W2, r2, WbT1, WbT2);
    rank_k<<<eb, 256, 0, stream>>>(dstp, et, bcnt, rank, E);
    scan1_k<<<NSB, 256, 0, stream>>>(bcnt, bsum);
    scan2_k<<<1, 512, 0, stream>>>(bsum, rstart, E);
    scan3_k<<<NSB, 256, 0, stream>>>(bcnt, bsum);
    scat_k<<<eb, 256, 0, stream>>>(srcp, dstp, et, rank, rstart, sedge, used, E);

    trans1_k<<<NGRP * TBLK, 256, 0, stream>>>(x, WbT1, b1, used, H1, X1m);
    edge1_k<<<(N_NODES + 3) / 4, 256, 0, stream>>>(sedge, rstart, H1, X1m);
    trans2_k<<<NGRP * TBLK, 256, 0, stream>>>(X1m, WbT2, b2, used, H2, out);
    edge2_k<<<(N_NODES / 4 + 3) / 4, 256, 0, stream>>>(sedge, rstart, H2, out);
}